// Round 7
// baseline (429.324 us; speedup 1.0000x reference)
//
#include <hip/hip_runtime.h>

typedef unsigned short ushort_t;
typedef unsigned int uint32;
typedef __attribute__((ext_vector_type(4))) float f32x4;
typedef __attribute__((ext_vector_type(8))) short bf16x8;

#define B_   4
#define S_   2048
#define D_   1024
#define H_   16
#define HD_  64
#define DFF_ 4096
#define M_   (B_ * S_)          // 8192 rows (tokens)

#define RES_   0.28867513459481287f   // 1/sqrt(12)
#define SCALE_ 0.03125f               // 1/sqrt(1024)
#define EPS_   1e-5f
#define LOG2E_ 1.4426950408889634f

__device__ __forceinline__ ushort_t f2bf(float f) {
    union { float f; uint32 u; } c; c.f = f;
    uint32 u = c.u + 0x7fffu + ((c.u >> 16) & 1u);
    return (ushort_t)(u >> 16);
}
__device__ __forceinline__ float bf2f(ushort_t h) {
    union { uint32 u; float f; } c; c.u = ((uint32)h) << 16;
    return c.f;
}
__device__ __forceinline__ float fexp2(float x) {
    float r; asm("v_exp_f32 %0, %1" : "=v"(r) : "v"(x)); return r;
}
__device__ __forceinline__ uint32 cvt_pk_bf16(float lo, float hi) {
    uint32 r;
    asm("v_cvt_pk_bf16_f32 %0, %1, %2" : "=v"(r) : "v"(lo), "v"(hi));
    return r;
}

#define GLDS(src_, dst_)                                                     \
    __builtin_amdgcn_global_load_lds(                                        \
        (const __attribute__((address_space(1))) void*)(src_),               \
        (__attribute__((address_space(3))) void*)(dst_), 16, 0, 0)

// ---------------------------------------------------------------------------
// Transpose + fp32->bf16 cast:  W[K][N] (fp32, row-major) -> Wt[N][K] (bf16)
// ---------------------------------------------------------------------------
__global__ __launch_bounds__(256) void transpose_cast_kernel(
    const float* __restrict__ W, ushort_t* __restrict__ Wt, int K, int N)
{
    __shared__ float tile[32][33];
    const int bx = blockIdx.x * 32;  // N offset
    const int by = blockIdx.y * 32;  // K offset
    const int tx = threadIdx.x;      // 0..31
    const int ty = threadIdx.y;      // 0..7
    #pragma unroll
    for (int i = 0; i < 32; i += 8)
        tile[ty + i][tx] = W[(size_t)(by + ty + i) * N + bx + tx];
    __syncthreads();
    #pragma unroll
    for (int i = 0; i < 32; i += 8)
        Wt[(size_t)(bx + ty + i) * K + by + tx] = f2bf(tile[tx][ty + i]);
}

// ---------------------------------------------------------------------------
// Concat bq,bk,bv -> bqkv[3072]
// ---------------------------------------------------------------------------
__global__ void concat_bias_kernel(const float* __restrict__ bq,
                                   const float* __restrict__ bk,
                                   const float* __restrict__ bv,
                                   float* __restrict__ bqkv)
{
    int i = blockIdx.x * blockDim.x + threadIdx.x;
    if (i < 3 * D_) {
        float v = (i < D_) ? bq[i] : (i < 2 * D_) ? bk[i - D_] : bv[i - 2 * D_];
        bqkv[i] = v;
    }
}

// ---------------------------------------------------------------------------
// LayerNorm: fp32 in [rows][1024] -> bf16 out
// ---------------------------------------------------------------------------
__global__ __launch_bounds__(256) void ln_kernel(
    const float* __restrict__ x, const float* __restrict__ g,
    const float* __restrict__ be, ushort_t* __restrict__ out)
{
    const int row = blockIdx.x;
    const int t = threadIdx.x;
    const int lane = t & 63;
    const int wave = t >> 6;
    const float4* xr = (const float4*)(x + (size_t)row * D_);
    float4 v = xr[t];
    float s  = v.x + v.y + v.z + v.w;
    float s2 = v.x * v.x + v.y * v.y + v.z * v.z + v.w * v.w;
    #pragma unroll
    for (int off = 32; off; off >>= 1) {
        s  += __shfl_xor(s, off);
        s2 += __shfl_xor(s2, off);
    }
    __shared__ float red[8];
    if (lane == 0) { red[wave * 2] = s; red[wave * 2 + 1] = s2; }
    __syncthreads();
    s  = red[0] + red[2] + red[4] + red[6];
    s2 = red[1] + red[3] + red[5] + red[7];
    const float mean = s * (1.0f / D_);
    const float var  = s2 * (1.0f / D_) - mean * mean;
    const float rstd = rsqrtf(var + EPS_);
    const float4 gv  = ((const float4*)g)[t];
    const float4 bv  = ((const float4*)be)[t];
    ushort_t o[4];
    o[0] = f2bf((v.x - mean) * rstd * gv.x + bv.x);
    o[1] = f2bf((v.y - mean) * rstd * gv.y + bv.y);
    o[2] = f2bf((v.z - mean) * rstd * gv.z + bv.z);
    o[3] = f2bf((v.w - mean) * rstd * gv.w + bv.w);
    *(ushort2*)&out[(size_t)row * D_ + t * 4]     = make_ushort2(o[0], o[1]);
    *(ushort2*)&out[(size_t)row * D_ + t * 4 + 2] = make_ushort2(o[2], o[3]);
}

// ---------------------------------------------------------------------------
// GEMM v4 (8-phase-style): C[M][N] = epilogue(A[M][K] @ Bt[N][K]^T + bias)
// BM=256, BN=128, BK=64, 8 waves (4M x 2N, 64x64/wave), 512 thr.
// 3-buffer LDS rotation (144KB), 4 phases/K-tile:
//   {ds_read subtile ; issue 2 gload_lds ; s_barrier ; setprio MFMA x8 ; s_barrier}
// vmcnt(6) once per tile (counted, never drained in steady state).
// T2 swizzle: linear LDS dest, inverse-swizzled GLOBAL source, swizzled reads
// (chunk ^= row&7 over 8 chunks -> 32 banks, 2-way = free).
// T1 bijective XCD swizzle (grids % 8 == 0).
// ---------------------------------------------------------------------------
template <int MODE>
__global__ __launch_bounds__(512, 1) void gemm8_kernel(
    const ushort_t* __restrict__ A, const ushort_t* __restrict__ Bt,
    const float* __restrict__ bias, const float* __restrict__ res,
    void* __restrict__ Cout, int M, int N, int K, int gx)
{
    __shared__ __align__(16) ushort_t As[3][256 * 64];   // 32KB x3
    __shared__ __align__(16) ushort_t Bs[3][128 * 64];   // 16KB x3

    const int tid  = threadIdx.x;
    const int w    = tid >> 6;
    const int lane = tid & 63;
    const int l15  = lane & 15;
    const int g    = lane >> 4;
    const int rp   = l15 & 7;            // row-parity for read swizzle

    // T1: bijective XCD swizzle (gridDim.x % 8 == 0)
    const int cpx = gridDim.x >> 3;
    const int swz = (blockIdx.x & 7) * cpx + (blockIdx.x >> 3);
    const int bx = swz % gx, by = swz / gx;
    const int m0 = by * 256, n0 = bx * 128;

    const int wm = (w >> 1) * 64;        // 0,64,128,192
    const int wn = (w & 1) * 64;         // 0,64

    // staging: A = 2048 chunks (4/thread), B = 1024 chunks (2/thread)
    // stored chunk (L&7) at row L>>3 holds logical chunk (L&7)^(row&7)
    const ushort_t* srcA[4];
    const ushort_t* srcB[2];
    int ldsA[4], ldsB[2];
    #pragma unroll
    for (int p = 0; p < 4; ++p) {
        const int L = p * 512 + tid;
        const int row = L >> 3;
        srcA[p] = A + (size_t)(m0 + row) * K + (((L & 7) ^ (row & 7)) << 3);
        ldsA[p] = (p * 512 + w * 64) * 8;     // wave-uniform; HW adds lane*16B
    }
    #pragma unroll
    for (int p = 0; p < 2; ++p) {
        const int L = p * 512 + tid;
        const int row = L >> 3;
        srcB[p] = Bt + (size_t)(n0 + row) * K + (((L & 7) ^ (row & 7)) << 3);
        ldsB[p] = (p * 512 + w * 64) * 8;
    }

    #define LDA(mf_, kk_)  (*(const bf16x8*)&Ac[(wm + (mf_) * 16 + l15) * 64 + \
                              ((((kk_) * 4 + g) ^ rp) << 3)])
    #define LDB(nf_, kk_)  (*(const bf16x8*)&Bc[(wn + (nf_) * 16 + l15) * 64 + \
                              ((((kk_) * 4 + g) ^ rp) << 3)])
    #define MM_PAIR(mfb_)                                                      \
        do {                                                                   \
            _Pragma("unroll")                                                  \
            for (int nf = 0; nf < 4; ++nf) {                                   \
                acc[(mfb_)][nf] = __builtin_amdgcn_mfma_f32_16x16x32_bf16(     \
                    a0, bb[nf], acc[(mfb_)][nf], 0, 0, 0);                     \
                acc[(mfb_) + 1][nf] = __builtin_amdgcn_mfma_f32_16x16x32_bf16( \
                    a1, bb[nf], acc[(mfb_) + 1][nf], 0, 0, 0);                 \
            }                                                                  \
        } while (0)

    f32x4 acc[4][4] = {};
    const int NT = K >> 6;

    // prologue: stage tiles 0,1; wait tile0 (6 of tile1 stay in flight)
    #pragma unroll
    for (int p = 0; p < 4; ++p) GLDS(srcA[p], &As[0][ldsA[p]]);
    #pragma unroll
    for (int p = 0; p < 2; ++p) GLDS(srcB[p], &Bs[0][ldsB[p]]);
    #pragma unroll
    for (int p = 0; p < 4; ++p) GLDS(srcA[p] + 64, &As[1][ldsA[p]]);
    #pragma unroll
    for (int p = 0; p < 2; ++p) GLDS(srcB[p] + 64, &Bs[1][ldsB[p]]);
    asm volatile("s_waitcnt vmcnt(6)" ::: "memory");
    __builtin_amdgcn_s_barrier();

    for (int t = 0; t < NT; ++t) {
        const int cur = t % 3;
        const int nb  = (t + 2) % 3;
        const bool st = (t + 2 < NT);
        const size_t koff = (size_t)(t + 2) * 64;
        const ushort_t* __restrict__ Ac = &As[cur][0];
        const ushort_t* __restrict__ Bc = &Bs[cur][0];

        bf16x8 bb[4], a0, a1;

        // ---- phase 0: B(kk0) + A mf0-1(kk0); stage A parts 0,1 ----
        #pragma unroll
        for (int nf = 0; nf < 4; ++nf) bb[nf] = LDB(nf, 0);
        a0 = LDA(0, 0); a1 = LDA(1, 0);
        if (st) { GLDS(srcA[0] + koff, &As[nb][ldsA[0]]);
                  GLDS(srcA[1] + koff, &As[nb][ldsA[1]]); }
        __builtin_amdgcn_s_barrier();
        __builtin_amdgcn_s_setprio(1);
        MM_PAIR(0);
        __builtin_amdgcn_s_setprio(0);
        __builtin_amdgcn_s_barrier();

        // ---- phase 1: A mf2-3(kk0); stage A parts 2,3 ----
        a0 = LDA(2, 0); a1 = LDA(3, 0);
        if (st) { GLDS(srcA[2] + koff, &As[nb][ldsA[2]]);
                  GLDS(srcA[3] + koff, &As[nb][ldsA[3]]); }
        __builtin_amdgcn_s_barrier();
        __builtin_amdgcn_s_setprio(1);
        MM_PAIR(2);
        __builtin_amdgcn_s_setprio(0);
        __builtin_amdgcn_s_barrier();

        // ---- phase 2: B(kk1) + A mf0-1(kk1); stage B parts ----
        #pragma unroll
        for (int nf = 0; nf < 4; ++nf) bb[nf] = LDB(nf, 1);
        a0 = LDA(0, 1); a1 = LDA(1, 1);
        if (st) { GLDS(srcB[0] + koff, &Bs[nb][ldsB[0]]);
                  GLDS(srcB[1] + koff, &Bs[nb][ldsB[1]]); }
        __builtin_amdgcn_s_barrier();
        __builtin_amdgcn_s_setprio(1);
        MM_PAIR(0);
        __builtin_amdgcn_s_setprio(0);
        __builtin_amdgcn_s_barrier();

        // ---- phase 3: A mf2-3(kk1); counted vmcnt, rotate ----
        a0 = LDA(2, 1); a1 = LDA(3, 1);
        __builtin_amdgcn_s_barrier();
        __builtin_amdgcn_s_setprio(1);
        MM_PAIR(2);
        __builtin_amdgcn_s_setprio(0);
        if (st) asm volatile("s_waitcnt vmcnt(6)" ::: "memory");
        else    asm volatile("s_waitcnt vmcnt(0)" ::: "memory");
        __builtin_amdgcn_s_barrier();
    }
    #undef LDA
    #undef LDB
    #undef MM_PAIR

    // epilogue: C/D layout col = lane&15, row = (lane>>4)*4 + r
    const int rbase = g * 4;
    #pragma unroll
    for (int mf = 0; mf < 4; ++mf) {
        #pragma unroll
        for (int nf = 0; nf < 4; ++nf) {
            const int col = n0 + wn + nf * 16 + l15;
            const float bcol = bias[col];
            #pragma unroll
            for (int r = 0; r < 4; ++r) {
                const int row = m0 + wm + mf * 16 + rbase + r;
                float v = acc[mf][nf][r] + bcol;
                const size_t idx = (size_t)row * N + col;
                if (MODE == 0) {
                    ((ushort_t*)Cout)[idx] = f2bf(v);
                } else if (MODE == 1) {
                    ((ushort_t*)Cout)[idx] = f2bf(fmaxf(v, 0.0f));
                } else {
                    ((float*)Cout)[idx] = res[idx] + RES_ * v;
                }
            }
        }
    }
}

// ---------------------------------------------------------------------------
// Flash attention v5 (causal) from packed qkv (bf16 [8192][3072]).
// - 64-row q-tiles, 4 waves x 16 rows; paired triangle (uniform 33 iters)
// - swapped QK^T, reg-prefetch staging (T14), exp2 softmax, defer-max (T13)
// out: bf16 [8192][1024]
// ---------------------------------------------------------------------------
__global__ __launch_bounds__(256) void fattn_kernel(
    const ushort_t* __restrict__ qkv, ushort_t* __restrict__ out)
{
    __shared__ __align__(16) ushort_t Ks[64 * 64];     // [key][d], chunk c^=key&7
    __shared__ __align__(16) ushort_t Vt[64 * 64];     // [d][key], chunk c^=(d&7)^((d>>3)&7)
    __shared__ __align__(16) ushort_t Ps[4][16 * 64];  // per-wave [q][key], 16B-chunk c16^=q&7

    const int tid  = threadIdx.x;
    const int lane = tid & 63;
    const int w    = tid >> 6;
    const int bh = blockIdx.y;
    const int b = bh >> 4, h = bh & 15;

    const int l15 = lane & 15;
    const int g   = lane >> 4;

    const size_t rs = 3 * D_;
    const ushort_t* Qg = qkv + (size_t)b * S_ * rs + h * HD_;
    const ushort_t* Kg = Qg + D_;

    // staging geometry (constant per thread)
    const int skey = tid >> 3;          // 0..31 (+32 on pass 1)
    const int sc   = tid & 7;           // 16B chunk within row

    #pragma unroll
    for (int half = 0; half < 2; ++half) {
        const int qt = half ? blockIdx.x : (S_ / 64 - 1) - blockIdx.x;
        const int q0 = qt * 64;
        const int nkb = qt + 1;

        // Q B-frags (col=q=l15, k=g*8+e +kk*32), pre-scaled by SCALE_*log2e
        bf16x8 qf[2];
        {
            const int qrow = q0 + w * 16 + l15;
            #pragma unroll
            for (int kk = 0; kk < 2; ++kk) {
                bf16x8 tq = *(const bf16x8*)(Qg + (size_t)qrow * rs + kk * 32 + g * 8);
                #pragma unroll
                for (int e = 0; e < 8; ++e)
                    tq[e] = (short)f2bf(bf2f((ushort_t)tq[e]) * (SCALE_ * LOG2E_));
                qf[kk] = tq;
            }
        }

        float mrow = -1e30f, lrow = 0.f;
        f32x4 oacc[4] = {};   // d-frags; D: col=d=l15, row(q-local)=g*4+r

        // prologue: load KV tile 0 into regs
        bf16x8 kvreg[2], vvreg[2];
        #pragma unroll
        for (int pass = 0; pass < 2; ++pass) {
            const ushort_t* src = Kg + (size_t)(pass * 32 + skey) * rs + sc * 8;
            kvreg[pass] = *(const bf16x8*)src;
            vvreg[pass] = *(const bf16x8*)(src + D_);
        }

        for (int kb = 0; kb < nkb; ++kb) {
            __syncthreads();   // prior compute done reading LDS
            // ---- write staged regs -> LDS (K swizzled b128, V^T scatter) ----
            #pragma unroll
            for (int pass = 0; pass < 2; ++pass) {
                const int key = pass * 32 + skey;
                *(bf16x8*)&Ks[key * 64 + ((sc ^ (key & 7)) << 3)] = kvreg[pass];
                #pragma unroll
                for (int j = 0; j < 8; ++j) {
                    const int d  = sc * 8 + j;
                    const int cp = (key >> 3) ^ (d & 7) ^ ((d >> 3) & 7);
                    Vt[d * 64 + (cp << 3) + (key & 7)] = (ushort_t)vvreg[pass][j];
                }
            }
            // ---- prefetch next KV tile into regs (hidden under compute) ----
            if (kb + 1 < nkb) {
                #pragma unroll
                for (int pass = 0; pass < 2; ++pass) {
                    const ushort_t* src =
                        Kg + (size_t)((kb + 1) * 64 + pass * 32 + skey) * rs + sc * 8;
                    kvreg[pass] = *(const bf16x8*)src;
                    vvreg[pass] = *(const bf16x8*)(src + D_);
                }
            }
            __syncthreads();   // staging visible

            // ---- S^T = K Q^T (D[key][q]: col=q=l15, row=key=g*4+r) ----
            f32x4 sf[4] = {};
            __builtin_amdgcn_s_setprio(1);
            #pragma unroll
            for (int kk = 0; kk < 2; ++kk) {
                const int cc = kk * 4 + g;
                #pragma unroll
                for (int nf = 0; nf < 4; ++nf) {
                    const int keyr = nf * 16 + l15;
                    bf16x8 kf = *(const bf16x8*)&Ks[keyr * 64 + ((cc ^ (keyr & 7)) << 3)];
                    sf[nf] = __builtin_amdgcn_mfma_f32_16x16x32_bf16(kf, qf[kk], sf[nf], 0, 0, 0);
                }
            }
            __builtin_amdgcn_s_setprio(0);

            // ---- mask (only last kv-block can cross the diagonal) ----
            if (kb == nkb - 1) {
                const int q = q0 + w * 16 + l15;
                #pragma unroll
                for (int nf = 0; nf < 4; ++nf)
                    #pragma unroll
                    for (int r = 0; r < 4; ++r)
                        if (kb * 64 + nf * 16 + g * 4 + r > q) sf[nf][r] = -1e30f;
            }
            // ---- per-row max ----
            float mx = -1e30f;
            #pragma unroll
            for (int nf = 0; nf < 4; ++nf)
                #pragma unroll
                for (int r = 0; r < 4; ++r) mx = fmaxf(mx, sf[nf][r]);
            mx = fmaxf(mx, __shfl_xor(mx, 16));
            mx = fmaxf(mx, __shfl_xor(mx, 32));

            // ---- deferred-max rescale (T13, THR=8 in log2 units) ----
            if (!__all(mx - mrow <= 8.0f)) {
                const float mnew = fmaxf(mrow, mx);
                const float corr = fexp2(mrow - mnew);
                mrow = mnew;
                lrow *= corr;
                #pragma unroll
                for (int r = 0; r < 4; ++r) {
                    const float cr = __shfl(corr, g * 4 + r, 16);
                    #pragma unroll
                    for (int nf = 0; nf < 4; ++nf) oacc[nf][r] *= cr;
                }
            }

            // ---- P = exp2(S - m), row-sum, packed write to Ps ----
            {
                const int qrow = l15;
                float psum = 0.f;
                #pragma unroll
                for (int nf = 0; nf < 4; ++nf) {
                    const float p0 = fexp2(sf[nf][0] - mrow);
                    const float p1 = fexp2(sf[nf][1] - mrow);
                    const float p2 = fexp2(sf[nf][2] - mrow);
                    const float p3 = fexp2(sf[nf][3] - mrow);
                    psum += (p0 + p1) + (p2 + p3);
                    uint2 pk = make_uint2(cvt_pk_bf16(p0, p1), cvt_pk_bf16(p2, p3));
                    const int c16 = ((nf << 1) + (g >> 1)) ^ (qrow & 7);
                    *(uint2*)((char*)Ps[w] + qrow * 128 + c16 * 16 + (g & 1) * 8) = pk;
                }
                psum += __shfl_xor(psum, 16);
                psum += __shfl_xor(psum, 32);
                lrow += psum;
            }

            // ---- O += P V (A=P from Ps, B=V^T from Vt) ----
            #pragma unroll
            for (int kk = 0; kk < 2; ++kk) {
                const int cc = kk * 4 + g;
                const int qrow = l15;
                const int c16 = cc ^ (qrow & 7);
                bf16x8 pa = *(const bf16x8*)((const char*)Ps[w] + qrow * 128 + c16 * 16);
                __builtin_amdgcn_s_setprio(1);
                #pragma unroll
                for (int nf = 0; nf < 4; ++nf) {
                    const int dr  = nf * 16 + l15;
                    const int cvp = cc ^ (dr & 7) ^ ((dr >> 3) & 7);
                    bf16x8 vf = *(const bf16x8*)&Vt[dr * 64 + (cvp << 3)];
                    oacc[nf] = __builtin_amdgcn_mfma_f32_16x16x32_bf16(pa, vf, oacc[nf], 0, 0, 0);
                }
                __builtin_amdgcn_s_setprio(0);
            }
        }

        // ---- epilogue: O = acc / l (l lives at lane l15=row; broadcast) ----
        const float linv = 1.0f / lrow;
        #pragma unroll
        for (int r = 0; r < 4; ++r) {
            const float li = __shfl(linv, g * 4 + r, 16);
            const int q = q0 + w * 16 + g * 4 + r;
            ushort_t* op = out + (size_t)(b * S_ + q) * D_ + h * HD_;
            #pragma unroll
            for (int nf = 0; nf < 4; ++nf)
                op[nf * 16 + l15] = f2bf(oacc[nf][r] * li);
        }
    }
}

// ---------------------------------------------------------------------------
// launch
// ---------------------------------------------------------------------------
extern "C" void kernel_launch(void* const* d_in, const int* in_sizes, int n_in,
                              void* d_out, int out_size, void* d_ws, size_t ws_size,
                              hipStream_t stream)
{
    const float* x   = (const float*)d_in[0];
    const float* Wq  = (const float*)d_in[1];
    const float* bq  = (const float*)d_in[2];
    const float* Wk  = (const float*)d_in[3];
    const float* bk  = (const float*)d_in[4];
    const float* Wv  = (const float*)d_in[5];
    const float* bv  = (const float*)d_in[6];
    const float* Wo  = (const float*)d_in[7];
    const float* bo  = (const float*)d_in[8];
    const float* g1  = (const float*)d_in[9];
    const float* be1 = (const float*)d_in[10];
    const float* g2  = (const float*)d_in[11];
    const float* be2 = (const float*)d_in[12];
    const float* W1  = (const float*)d_in[13];
    const float* b1  = (const float*)d_in[14];
    const float* W2  = (const float*)d_in[15];
    const float* b2  = (const float*)d_in[16];
    float* out = (float*)d_out;

    char* ws = (char*)d_ws;
    size_t o = 0;
    auto alloc = [&](size_t bytes) { size_t r = o; o = (o + bytes + 255) & ~(size_t)255; return r; };
    ushort_t* Wqkvt = (ushort_t*)(ws + alloc((size_t)3 * D_ * D_ * 2));   // [3072][1024]
    ushort_t* Wot   = (ushort_t*)(ws + alloc((size_t)D_ * D_ * 2));      // [1024][1024]
    ushort_t* W1t   = (ushort_t*)(ws + alloc((size_t)DFF_ * D_ * 2));    // [4096][1024]
    ushort_t* W2t   = (ushort_t*)(ws + alloc((size_t)D_ * DFF_ * 2));    // [1024][4096]
    float*    bqkv  = (float*)(ws + alloc((size_t)3 * D_ * 4));
    ushort_t* lnbuf = (ushort_t*)(ws + alloc((size_t)M_ * D_ * 2));      // ln1 then ln2
    ushort_t* bigbuf= (ushort_t*)(ws + alloc((size_t)M_ * DFF_ * 2));    // qkv then ffn-hidden
    ushort_t* attnb = (ushort_t*)(ws + alloc((size_t)M_ * D_ * 2));
    float*    x1    = (float*)(ws + alloc((size_t)M_ * D_ * 4));

    dim3 tblock(32, 8);
    transpose_cast_kernel<<<dim3(D_/32, D_/32), tblock, 0, stream>>>(Wq, Wqkvt,            D_, D_);
    transpose_cast_kernel<<<dim3(D_/32, D_/32), tblock, 0, stream>>>(Wk, Wqkvt + D_*D_,    D_, D_);
    transpose_cast_kernel<<<dim3(D_/32, D_/32), tblock, 0, stream>>>(Wv, Wqkvt + 2*D_*D_,  D_, D_);
    transpose_cast_kernel<<<dim3(D_/32, D_/32), tblock, 0, stream>>>(Wo, Wot,              D_, D_);
    transpose_cast_kernel<<<dim3(DFF_/32, D_/32), tblock, 0, stream>>>(W1, W1t,            D_, DFF_);
    transpose_cast_kernel<<<dim3(D_/32, DFF_/32), tblock, 0, stream>>>(W2, W2t,            DFF_, D_);
    concat_bias_kernel<<<12, 256, 0, stream>>>(bq, bk, bv, bqkv);

    // ln1
    ln_kernel<<<M_, 256, 0, stream>>>(x, g1, be1, lnbuf);
    // qkv = ln1 @ Wqkv + bqkv          [8192][3072] bf16   grid 32*24=768
    gemm8_kernel<0><<<(M_/256)*(3*D_/128), 512, 0, stream>>>(
        lnbuf, Wqkvt, bqkv, nullptr, bigbuf, M_, 3*D_, D_, 3*D_/128);
    // flash attention (paired q-tiles)  [8192][1024] bf16
    fattn_kernel<<<dim3(S_/128, B_*H_), 256, 0, stream>>>(bigbuf, attnb);
    // x1 = x + RES*(attn @ Wo + bo)     [8192][1024] fp32  grid 32*8=256
    gemm8_kernel<2><<<(M_/256)*(D_/128), 512, 0, stream>>>(
        attnb, Wot, bo, x, x1, M_, D_, D_, D_/128);
    // ln2
    ln_kernel<<<M_, 256, 0, stream>>>(x1, g2, be2, lnbuf);
    // ffh = relu(ln2 @ W1 + b1)         [8192][4096] bf16  grid 32*32=1024
    gemm8_kernel<1><<<(M_/256)*(DFF_/128), 512, 0, stream>>>(
        lnbuf, W1t, b1, nullptr, bigbuf, M_, DFF_, D_, DFF_/128);
    // out = x1 + RES*(ffh @ W2 + b2)    [8192][1024] fp32  grid 32*8=256
    gemm8_kernel<2><<<(M_/256)*(D_/128), 512, 0, stream>>>(
        bigbuf, W2t, b2, x1, out, M_, D_, DFF_, D_/128);
}